// Round 5
// baseline (345.053 us; speedup 1.0000x reference)
//
#include <hip/hip_runtime.h>
#include <math.h>

#define Bn 32
#define Ln 512
#define Hn 256
#define NHn 4
#define DHn 64

typedef __attribute__((ext_vector_type(8))) short bf16x8;
typedef __attribute__((ext_vector_type(4))) float f32x4;
typedef unsigned int uint32;

__device__ __forceinline__ short f2b(float f) {
    union { float f; uint32 u; } v; v.f = f;
    uint32 r = (v.u + 0x7FFFu + ((v.u >> 16) & 1u)) >> 16;
    return (short)r;
}
__device__ __forceinline__ float b2f(short h) {
    union { uint32 u; float f; } v; v.u = ((uint32)(unsigned short)h) << 16;
    return v.f;
}
// fast tanh: 1 - 2/(e^{2x}+1); exact limits at +-inf
__device__ __forceinline__ float fast_tanh(float x) {
    float e = __expf(2.f * x);
    return 1.f - 2.f * __builtin_amdgcn_rcpf(e + 1.f);
}
__device__ __forceinline__ float fast_sigmoid(float x) {
    return __builtin_amdgcn_rcpf(1.f + __expf(-x));
}

// ---------------- fp32 -> bf16 conversion: x (B*L*H) and 5 weight mats ----------------
__global__ __launch_bounds__(256) void conv_kernel(
    const float* __restrict__ x,
    const float* __restrict__ Wq, const float* __restrict__ Wk,
    const float* __restrict__ Wv, const float* __restrict__ Wtq,
    const float* __restrict__ Wd,
    short* __restrict__ xb, short* __restrict__ wb)
{
    const size_t NLH = (size_t)Bn * Ln * Hn;
    size_t i4 = ((size_t)blockIdx.x * 256 + threadIdx.x) * 4;
    if (i4 < NLH) {
        float4 v = *(const float4*)(x + i4);
        short4 o; o.x = f2b(v.x); o.y = f2b(v.y); o.z = f2b(v.z); o.w = f2b(v.w);
        *(short4*)(xb + i4) = o;
    } else {
        size_t off = i4 - NLH;                 // < 5*65536
        int w = (int)(off >> 16);
        size_t wi = off & 65535;
        const float* src = (w == 0) ? Wq : (w == 1) ? Wk : (w == 2) ? Wv : (w == 3) ? Wtq : Wd;
        float4 v = *(const float4*)(src + wi);
        short4 o; o.x = f2b(v.x); o.y = f2b(v.y); o.z = f2b(v.z); o.w = f2b(v.w);
        *(short4*)(wb + off) = o;
    }
}

// ---------------- shared 64x64 bf16 MFMA NT-GEMM tile (K multiple of 64) ----------------
struct Acc { f32x4 t[4]; };

__device__ __forceinline__ void gemm_tile_64(
    const short* __restrict__ A,   // rows m0.., row stride K
    const short* __restrict__ Bm,  // rows n0.., row stride K
    int K, short* As, short* Bs, Acc& acc)
{
    const int tid = threadIdx.x;
    const int lane = tid & 63, w = tid >> 6;
    const int quad = lane >> 4, lm = lane & 15;
    const int srow = tid >> 3;   // 0..31
    const int slot = tid & 7;

    for (int k0 = 0; k0 < K; k0 += 64) {
        __syncthreads();
#pragma unroll
        for (int iss = 0; iss < 2; ++iss) {
            int r = srow + iss * 32;
            bf16x8 av = *(const bf16x8*)(A + (size_t)r * K + k0 + slot * 8);
            bf16x8 bv = *(const bf16x8*)(Bm + (size_t)r * K + k0 + slot * 8);
            *(bf16x8*)(As + r * 72 + slot * 8) = av;
            *(bf16x8*)(Bs + r * 72 + slot * 8) = bv;
        }
        __syncthreads();
#pragma unroll
        for (int ks = 0; ks < 2; ++ks) {
            bf16x8 a = *(const bf16x8*)(As + (w * 16 + lm) * 72 + ks * 32 + quad * 8);
#pragma unroll
            for (int kt = 0; kt < 4; ++kt) {
                bf16x8 b = *(const bf16x8*)(Bs + (kt * 16 + lm) * 72 + ks * 32 + quad * 8);
                acc.t[kt] = __builtin_amdgcn_mfma_f32_16x16x32_bf16(a, b, acc.t[kt], 0, 0, 0);
            }
        }
    }
}

// ---------------- fused QKV+TQ projection ----------------
__global__ __launch_bounds__(256) void proj_kernel(
    const short* __restrict__ xb, const short* __restrict__ wb,
    const float* __restrict__ bq, const float* __restrict__ bk,
    const float* __restrict__ bv, const float* __restrict__ btq,
    short* __restrict__ qb, short* __restrict__ kb,
    short* __restrict__ vb, short* __restrict__ tqb)
{
    __shared__ short As[64 * 72];
    __shared__ short Bs[64 * 72];
    const int tensor = blockIdx.x >> 2;
    const int ncol0 = (blockIdx.x & 3) * 64;
    const int m0 = blockIdx.y * 64;
    const short* A = xb + (size_t)m0 * Hn;
    const short* Bw = wb + (size_t)tensor * 65536 + (size_t)ncol0 * Hn;
    const float* bias = (tensor == 0) ? bq : (tensor == 1) ? bk : (tensor == 2) ? bv : btq;
    short* out = (tensor == 0) ? qb : (tensor == 1) ? kb : (tensor == 2) ? vb : tqb;

    Acc acc;
#pragma unroll
    for (int i = 0; i < 4; ++i) acc.t[i] = (f32x4){0.f, 0.f, 0.f, 0.f};
    gemm_tile_64(A, Bw, Hn, As, Bs, acc);

    const int lane = threadIdx.x & 63, w = threadIdx.x >> 6;
    const int quad = lane >> 4, lm = lane & 15;
#pragma unroll
    for (int kt = 0; kt < 4; ++kt) {
        int n = ncol0 + kt * 16 + lm;
        float bs = bias[n];
#pragma unroll
        for (int r = 0; r < 4; ++r) {
            int row = m0 + w * 16 + quad * 4 + r;
            out[(size_t)row * Hn + n] = f2b(acc.t[kt][r] + bs);
        }
    }
}

// ---------------- time-decay gate (bf16 out, includes /sqrt(DH)) ----------------
__global__ __launch_bounds__(256) void gate_kernel(
    const short* __restrict__ tqb, const short* __restrict__ xb,
    const float* __restrict__ tseq,
    const float* __restrict__ tw1, const float* __restrict__ tb1,
    const float* __restrict__ tow1, const float* __restrict__ tow2,
    const float* __restrict__ tob,
    short* __restrict__ gateb)
{
    __shared__ short As[64 * 72];
    __shared__ short Bs[64 * 72];
    const int b = blockIdx.z;
    const int m0 = blockIdx.y * 64, n0 = blockIdx.x * 64;
    const short* A = tqb + ((size_t)b * Ln + m0) * Hn;
    const short* Bw = xb + ((size_t)b * Ln + n0) * Hn;

    Acc acc;
#pragma unroll
    for (int i = 0; i < 4; ++i) acc.t[i] = (f32x4){0.f, 0.f, 0.f, 0.f};
    gemm_tile_64(A, Bw, Hn, As, Bs, acc);

    const int lane = threadIdx.x & 63, w = threadIdx.x >> 6;
    const int quad = lane >> 4, lm = lane & 15;
    const float* ts = tseq + (size_t)b * Ln;
    float ti[4];
#pragma unroll
    for (int r = 0; r < 4; ++r) ti[r] = ts[m0 + w * 16 + quad * 4 + r];
#pragma unroll
    for (int kt = 0; kt < 4; ++kt) {
        int j = n0 + kt * 16 + lm;
        float tj = ts[j];
#pragma unroll
        for (int r = 0; r < 4; ++r) {
            int i = m0 + w * 16 + quad * 4 + r;
            size_t ij = (size_t)i * Ln + j;
            float lg = __logf(1.f + fabsf(ti[r] - tj));
            float dec = fast_tanh(lg * tw1[ij] + tb1[ij]);
            float tqk = fast_tanh(acc.t[kt][r]);
            float dg = tow1[ij] * dec + tow2[ij] * tqk + tob[ij];
            float g = 0.125f * fast_sigmoid(dg);
            gateb[(size_t)b * Ln * Ln + ij] = f2b(g);
        }
    }
}

// ---------------- flash attention, bf16 MFMA ----------------
// block = 256 threads = 4 waves; wave w = head w; q-tile = 16 rows (shared by
// all waves). Gate/mask addresses identical across waves -> L1 broadcast, HBM
// reads them once. Each wave stages ONLY its head's V slice (stride 72 = 144B
// rows, 16B-aligned for ds_read_b128; paired-key u32 writes -> <=2-way
// conflicts = free) and owns a private P tile -> NO __syncthreads anywhere.
// K consumed as direct global B-frags (L2-resident). No-max softmax (scores
// bounded: gate=sigmoid/8, 0.02-scale weights -> |s*g| << 88).
__global__ __launch_bounds__(256) void flash_mfma(
    const short* __restrict__ qb, const short* __restrict__ kb,
    const short* __restrict__ vb, const short* __restrict__ gateb,
    const float* __restrict__ mask, short* __restrict__ ctxb)
{
    __shared__ short Vt[256 * 72];       // [d 0..255][key 0..63]; wave w owns d in [w*64, w*64+64)
    __shared__ short Ps[4 * 16 * 72];    // per-wave P tile [16 q][64 k]
    const int q0 = blockIdx.x * 16;
    const int b = blockIdx.y;
    const int tid = threadIdx.x;
    const int h = tid >> 6, lane = tid & 63;    // wave index == head
    const int quad = lane >> 4, lm = lane & 15;

    // Q A-frag for this head (A: row m=lm, k=quad*8+j)
    bf16x8 qf0, qf1;
    {
        const short* qrow = qb + ((size_t)(b * Ln + q0 + lm)) * Hn + h * DHn;
        qf0 = *(const bf16x8*)(qrow + quad * 8);
        qf1 = *(const bf16x8*)(qrow + 32 + quad * 8);
    }

    f32x4 o[4];
#pragma unroll
    for (int i = 0; i < 4; ++i) o[i] = (f32x4){0.f, 0.f, 0.f, 0.f};
    float lpart[4] = {0.f, 0.f, 0.f, 0.f};

    const int qrow0 = q0 + quad * 4;
    const short* gr = gateb + (size_t)b * Ln * Ln;
    const float* mk = mask + (size_t)b * Ln * Ln;
    const int kp = lane & 31;            // key pair index
    const int dh = lane >> 5;            // 0..1
    short* vt = Vt + h * DHn * 72;       // wave-private V^T region
    short* pw = Ps + h * 16 * 72;        // wave-private P region

    for (int k0 = 0; k0 < Ln; k0 += 64) {
        // stage this head's V slice transposed: vt[d][key], d in [0,64)
        {
            const short* vbase = vb + ((size_t)(b * Ln + k0)) * Hn + h * DHn;
            const short* va_p = vbase + (size_t)(2 * kp) * Hn;
            const short* vc_p = vbase + (size_t)(2 * kp + 1) * Hn;
#pragma unroll
            for (int it = 0; it < 4; ++it) {
                int dg = dh + it * 2;                 // 0..7
                bf16x8 va = *(const bf16x8*)(va_p + dg * 8);
                bf16x8 vc = *(const bf16x8*)(vc_p + dg * 8);
#pragma unroll
                for (int u = 0; u < 8; ++u) {
                    uint32 pk = (uint32)(unsigned short)va[u] |
                                ((uint32)(unsigned short)vc[u] << 16);
                    *(uint32*)&vt[(dg * 8 + u) * 72 + 2 * kp] = pk;
                }
            }
        }
        // (no barrier: wave-private LDS, compiler inserts lgkmcnt waits)

        // S = Q K^T, K B-frags straight from global (L2)
        const short* kbase = kb + ((size_t)(b * Ln + k0)) * Hn + h * DHn;
        f32x4 s[4];
#pragma unroll
        for (int kt = 0; kt < 4; ++kt) {
            const short* krow = kbase + (size_t)(kt * 16 + lm) * Hn;
            s[kt] = (f32x4){0.f, 0.f, 0.f, 0.f};
            bf16x8 b0 = *(const bf16x8*)(krow + quad * 8);
            s[kt] = __builtin_amdgcn_mfma_f32_16x16x32_bf16(qf0, b0, s[kt], 0, 0, 0);
            bf16x8 b1 = *(const bf16x8*)(krow + 32 + quad * 8);
            s[kt] = __builtin_amdgcn_mfma_f32_16x16x32_bf16(qf1, b1, s[kt], 0, 0, 0);
        }

        // p = exp(s*g + m); accumulate l; write P tile (gate/mask shared across waves via L1)
#pragma unroll
        for (int kt = 0; kt < 4; ++kt) {
            int col = k0 + kt * 16 + lm;
#pragma unroll
            for (int r = 0; r < 4; ++r) {
                size_t idx = (size_t)(qrow0 + r) * Ln + col;
                float pv = __expf(s[kt][r] * b2f(gr[idx]) + mk[idx]);
                lpart[r] += pv;
                pw[(quad * 4 + r) * 72 + kt * 16 + lm] = f2b(pv);
            }
        }
        // PV
#pragma unroll
        for (int ks = 0; ks < 2; ++ks) {
            bf16x8 pa = *(const bf16x8*)(pw + lm * 72 + ks * 32 + quad * 8);
#pragma unroll
            for (int ot = 0; ot < 4; ++ot) {
                bf16x8 vv = *(const bf16x8*)(vt + (ot * 16 + lm) * 72 + ks * 32 + quad * 8);
                o[ot] = __builtin_amdgcn_mfma_f32_16x16x32_bf16(pa, vv, o[ot], 0, 0, 0);
            }
        }
    }

    // final l reduction (16 lanes within quad) + normalize + store
#pragma unroll
    for (int r = 0; r < 4; ++r) {
        float lv = lpart[r];
#pragma unroll
        for (int off = 1; off < 16; off <<= 1) lv += __shfl_xor(lv, off, 64);
        float inv = 1.0f / lv;
        int row = b * Ln + qrow0 + r;
#pragma unroll
        for (int ot = 0; ot < 4; ++ot) {
            int d = h * DHn + ot * 16 + lm;
            ctxb[(size_t)row * Hn + d] = f2b(o[ot][r] * inv);
        }
    }
}

// ---------------- output projection + residual (fp32 out) ----------------
__global__ __launch_bounds__(256) void outproj_kernel(
    const short* __restrict__ ctxb, const short* __restrict__ wdb,
    const float* __restrict__ bd, const float* __restrict__ x,
    float* __restrict__ out)
{
    __shared__ short As[64 * 72];
    __shared__ short Bs[64 * 72];
    const int n0 = blockIdx.x * 64, m0 = blockIdx.y * 64;
    Acc acc;
#pragma unroll
    for (int i = 0; i < 4; ++i) acc.t[i] = (f32x4){0.f, 0.f, 0.f, 0.f};
    gemm_tile_64(ctxb + (size_t)m0 * Hn, wdb + (size_t)n0 * Hn, Hn, As, Bs, acc);

    const int lane = threadIdx.x & 63, w = threadIdx.x >> 6;
    const int quad = lane >> 4, lm = lane & 15;
#pragma unroll
    for (int kt = 0; kt < 4; ++kt) {
        int n = n0 + kt * 16 + lm;
        float bs = bd[n];
#pragma unroll
        for (int r = 0; r < 4; ++r) {
            int row = m0 + w * 16 + quad * 4 + r;
            out[(size_t)row * Hn + n] = acc.t[kt][r] + bs + x[(size_t)row * Hn + n];
        }
    }
}

// ---------------- in-place LayerNorm over H=256 ----------------
__global__ __launch_bounds__(256) void ln_kernel(float* __restrict__ hs,
                                                 const float* __restrict__ g,
                                                 const float* __restrict__ bta)
{
    const int row = blockIdx.x, t = threadIdx.x;
    float v = hs[(size_t)row * Hn + t];
    float s1 = v, s2 = v * v;
#pragma unroll
    for (int off = 32; off > 0; off >>= 1) {
        s1 += __shfl_xor(s1, off, 64);
        s2 += __shfl_xor(s2, off, 64);
    }
    __shared__ float red[8];
    if ((t & 63) == 0) { red[t >> 6] = s1; red[4 + (t >> 6)] = s2; }
    __syncthreads();
    float sum = red[0] + red[1] + red[2] + red[3];
    float sq  = red[4] + red[5] + red[6] + red[7];
    float mu  = sum * (1.f / 256.f);
    float var = sq * (1.f / 256.f) - mu * mu;
    float rstd = rsqrtf(var + 1e-12f);
    hs[(size_t)row * Hn + t] = (v - mu) * rstd * g[t] + bta[t];
}

// ---------------- prediction head ----------------
__global__ __launch_bounds__(256) void pred_kernel(const float* __restrict__ hs,
                                                   const int* __restrict__ lens,
                                                   const float* __restrict__ Wt,
                                                   const float* __restrict__ bt,
                                                   float* __restrict__ pred)
{
    const int b = blockIdx.x, t = threadIdx.x;
    int len = lens[b];
    float e1 = hs[((size_t)b * Ln + (len - 1)) * Hn + t];
    float e2 = hs[((size_t)b * Ln + (len - 2)) * Hn + t];
    float v = e1 * Wt[t] + e2 * Wt[Hn + t];
#pragma unroll
    for (int off = 32; off > 0; off >>= 1) v += __shfl_xor(v, off, 64);
    __shared__ float ps[4];
    if ((t & 63) == 0) ps[t >> 6] = v;
    __syncthreads();
    if (t == 0) pred[b] = ps[0] + ps[1] + ps[2] + ps[3] + bt[0];
}

extern "C" void kernel_launch(void* const* d_in, const int* in_sizes, int n_in,
                              void* d_out, int out_size, void* d_ws, size_t ws_size,
                              hipStream_t stream) {
    (void)in_sizes; (void)n_in; (void)out_size; (void)ws_size;
    const float* x    = (const float*)d_in[0];
    const float* tseq = (const float*)d_in[1];
    const float* mask = (const float*)d_in[2];
    const int*   lens = (const int*)d_in[3];
    const float* Wq = (const float*)d_in[4];  const float* bq = (const float*)d_in[5];
    const float* Wk = (const float*)d_in[6];  const float* bk = (const float*)d_in[7];
    const float* Wv = (const float*)d_in[8];  const float* bv = (const float*)d_in[9];
    const float* Wd = (const float*)d_in[10]; const float* bd = (const float*)d_in[11];
    const float* ln_g = (const float*)d_in[12]; const float* ln_b = (const float*)d_in[13];
    const float* Wtq = (const float*)d_in[14]; const float* btq = (const float*)d_in[15];
    const float* tw1 = (const float*)d_in[16]; const float* tb1 = (const float*)d_in[17];
    const float* tow1 = (const float*)d_in[18]; const float* tow2 = (const float*)d_in[19];
    const float* tob = (const float*)d_in[20];
    const float* Wt = (const float*)d_in[21]; const float* bt = (const float*)d_in[22];

    const size_t NLH = (size_t)Bn * Ln * Hn;   // 4194304
    short* ws = (short*)d_ws;
    short* xb    = ws;
    short* wb    = xb + NLH;                   // 5*65536
    short* qb    = wb + 5 * 65536;
    short* kb    = qb + NLH;
    short* vb    = kb + NLH;
    short* tqb   = vb + NLH;
    short* gateb = tqb + NLH;                  // B*L*L
    short* ctxb  = gateb + (size_t)Bn * Ln * Ln;
    float* out   = (float*)d_out;

    dim3 blk(256);
    conv_kernel<<<dim3(4416), blk, 0, stream>>>(x, Wq, Wk, Wv, Wtq, Wd, xb, wb);
    proj_kernel<<<dim3(16, 256), blk, 0, stream>>>(xb, wb, bq, bk, bv, btq, qb, kb, vb, tqb);
    gate_kernel<<<dim3(8, 8, Bn), blk, 0, stream>>>(tqb, xb, tseq, tw1, tb1, tow1, tow2, tob, gateb);
    flash_mfma<<<dim3(32, 32), blk, 0, stream>>>(qb, kb, vb, gateb, mask, ctxb);
    outproj_kernel<<<dim3(4, 256), blk, 0, stream>>>(ctxb, wb + 4 * 65536, bd, x, out);
    ln_kernel<<<dim3(Bn * Ln), blk, 0, stream>>>(out, ln_g, ln_b);
    pred_kernel<<<dim3(Bn), blk, 0, stream>>>(out, lens, Wt, bt, out + NLH);
}

// Round 6
// 258.962 us; speedup vs baseline: 1.3324x; 1.3324x over previous
//
#include <hip/hip_runtime.h>
#include <math.h>

#define Bn 32
#define Ln 512
#define Hn 256
#define NHn 4
#define DHn 64

typedef __attribute__((ext_vector_type(8))) short bf16x8;
typedef __attribute__((ext_vector_type(4))) float f32x4;
typedef unsigned int uint32;

__device__ __forceinline__ short f2b(float f) {
    union { float f; uint32 u; } v; v.f = f;
    uint32 r = (v.u + 0x7FFFu + ((v.u >> 16) & 1u)) >> 16;
    return (short)r;
}
__device__ __forceinline__ float b2f(short h) {
    union { uint32 u; float f; } v; v.u = ((uint32)(unsigned short)h) << 16;
    return v.f;
}
// fast tanh: 1 - 2/(e^{2x}+1); exact limits at +-inf
__device__ __forceinline__ float fast_tanh(float x) {
    float e = __expf(2.f * x);
    return 1.f - 2.f * __builtin_amdgcn_rcpf(e + 1.f);
}
__device__ __forceinline__ float fast_sigmoid(float x) {
    return __builtin_amdgcn_rcpf(1.f + __expf(-x));
}

// ---------------- fp32 -> bf16 conversion: x (B*L*H) and 5 weight mats ----------------
__global__ __launch_bounds__(256) void conv_kernel(
    const float* __restrict__ x,
    const float* __restrict__ Wq, const float* __restrict__ Wk,
    const float* __restrict__ Wv, const float* __restrict__ Wtq,
    const float* __restrict__ Wd,
    short* __restrict__ xb, short* __restrict__ wb)
{
    const size_t NLH = (size_t)Bn * Ln * Hn;
    size_t i4 = ((size_t)blockIdx.x * 256 + threadIdx.x) * 4;
    if (i4 < NLH) {
        float4 v = *(const float4*)(x + i4);
        short4 o; o.x = f2b(v.x); o.y = f2b(v.y); o.z = f2b(v.z); o.w = f2b(v.w);
        *(short4*)(xb + i4) = o;
    } else {
        size_t off = i4 - NLH;                 // < 5*65536
        int w = (int)(off >> 16);
        size_t wi = off & 65535;
        const float* src = (w == 0) ? Wq : (w == 1) ? Wk : (w == 2) ? Wv : (w == 3) ? Wtq : Wd;
        float4 v = *(const float4*)(src + wi);
        short4 o; o.x = f2b(v.x); o.y = f2b(v.y); o.z = f2b(v.z); o.w = f2b(v.w);
        *(short4*)(wb + off) = o;
    }
}

// ---------------- shared 64x64 bf16 MFMA NT-GEMM tile (K multiple of 64) ----------------
struct Acc { f32x4 t[4]; };

__device__ __forceinline__ void gemm_tile_64(
    const short* __restrict__ A,   // rows m0.., row stride K
    const short* __restrict__ Bm,  // rows n0.., row stride K
    int K, short* As, short* Bs, Acc& acc)
{
    const int tid = threadIdx.x;
    const int lane = tid & 63, w = tid >> 6;
    const int quad = lane >> 4, lm = lane & 15;
    const int srow = tid >> 3;   // 0..31
    const int slot = tid & 7;

    for (int k0 = 0; k0 < K; k0 += 64) {
        __syncthreads();
#pragma unroll
        for (int iss = 0; iss < 2; ++iss) {
            int r = srow + iss * 32;
            bf16x8 av = *(const bf16x8*)(A + (size_t)r * K + k0 + slot * 8);
            bf16x8 bv = *(const bf16x8*)(Bm + (size_t)r * K + k0 + slot * 8);
            *(bf16x8*)(As + r * 72 + slot * 8) = av;
            *(bf16x8*)(Bs + r * 72 + slot * 8) = bv;
        }
        __syncthreads();
#pragma unroll
        for (int ks = 0; ks < 2; ++ks) {
            bf16x8 a = *(const bf16x8*)(As + (w * 16 + lm) * 72 + ks * 32 + quad * 8);
#pragma unroll
            for (int kt = 0; kt < 4; ++kt) {
                bf16x8 b = *(const bf16x8*)(Bs + (kt * 16 + lm) * 72 + ks * 32 + quad * 8);
                acc.t[kt] = __builtin_amdgcn_mfma_f32_16x16x32_bf16(a, b, acc.t[kt], 0, 0, 0);
            }
        }
    }
}

// ---------------- fused QKV+TQ projection ----------------
__global__ __launch_bounds__(256) void proj_kernel(
    const short* __restrict__ xb, const short* __restrict__ wb,
    const float* __restrict__ bq, const float* __restrict__ bk,
    const float* __restrict__ bv, const float* __restrict__ btq,
    short* __restrict__ qb, short* __restrict__ kb,
    short* __restrict__ vb, short* __restrict__ tqb)
{
    __shared__ short As[64 * 72];
    __shared__ short Bs[64 * 72];
    const int tensor = blockIdx.x >> 2;
    const int ncol0 = (blockIdx.x & 3) * 64;
    const int m0 = blockIdx.y * 64;
    const short* A = xb + (size_t)m0 * Hn;
    const short* Bw = wb + (size_t)tensor * 65536 + (size_t)ncol0 * Hn;
    const float* bias = (tensor == 0) ? bq : (tensor == 1) ? bk : (tensor == 2) ? bv : btq;
    short* out = (tensor == 0) ? qb : (tensor == 1) ? kb : (tensor == 2) ? vb : tqb;

    Acc acc;
#pragma unroll
    for (int i = 0; i < 4; ++i) acc.t[i] = (f32x4){0.f, 0.f, 0.f, 0.f};
    gemm_tile_64(A, Bw, Hn, As, Bs, acc);

    const int lane = threadIdx.x & 63, w = threadIdx.x >> 6;
    const int quad = lane >> 4, lm = lane & 15;
#pragma unroll
    for (int kt = 0; kt < 4; ++kt) {
        int n = ncol0 + kt * 16 + lm;
        float bs = bias[n];
#pragma unroll
        for (int r = 0; r < 4; ++r) {
            int row = m0 + w * 16 + quad * 4 + r;
            out[(size_t)row * Hn + n] = f2b(acc.t[kt][r] + bs);
        }
    }
}

// ---------------- time-decay gate: packs {bf16 gate*0.125, bf16 mask} into u32 ----------------
__global__ __launch_bounds__(256) void gate_kernel(
    const short* __restrict__ tqb, const short* __restrict__ xb,
    const float* __restrict__ tseq, const float* __restrict__ mask,
    const float* __restrict__ tw1, const float* __restrict__ tb1,
    const float* __restrict__ tow1, const float* __restrict__ tow2,
    const float* __restrict__ tob,
    uint32* __restrict__ gm)
{
    __shared__ short As[64 * 72];
    __shared__ short Bs[64 * 72];
    const int b = blockIdx.z;
    const int m0 = blockIdx.y * 64, n0 = blockIdx.x * 64;
    const short* A = tqb + ((size_t)b * Ln + m0) * Hn;
    const short* Bw = xb + ((size_t)b * Ln + n0) * Hn;

    Acc acc;
#pragma unroll
    for (int i = 0; i < 4; ++i) acc.t[i] = (f32x4){0.f, 0.f, 0.f, 0.f};
    gemm_tile_64(A, Bw, Hn, As, Bs, acc);

    const int lane = threadIdx.x & 63, w = threadIdx.x >> 6;
    const int quad = lane >> 4, lm = lane & 15;
    const float* ts = tseq + (size_t)b * Ln;
    const float* mk = mask + (size_t)b * Ln * Ln;
    uint32* gout = gm + (size_t)b * Ln * Ln;
    float ti[4];
#pragma unroll
    for (int r = 0; r < 4; ++r) ti[r] = ts[m0 + w * 16 + quad * 4 + r];
#pragma unroll
    for (int kt = 0; kt < 4; ++kt) {
        int j = n0 + kt * 16 + lm;
        float tj = ts[j];
#pragma unroll
        for (int r = 0; r < 4; ++r) {
            int i = m0 + w * 16 + quad * 4 + r;
            size_t ij = (size_t)i * Ln + j;
            float lg = __logf(1.f + fabsf(ti[r] - tj));
            float dec = fast_tanh(lg * tw1[ij] + tb1[ij]);
            float tqk = fast_tanh(acc.t[kt][r]);
            float dg = tow1[ij] * dec + tow2[ij] * tqk + tob[ij];
            float g = 0.125f * fast_sigmoid(dg);
            uint32 pk = (uint32)(unsigned short)f2b(g) |
                        ((uint32)(unsigned short)f2b(mk[ij]) << 16);
            gout[ij] = pk;
        }
    }
}

// ---------------- flash attention (r3 structure + fixes) ----------------
// block=256 (4 waves), one head per block, 64 q-rows. K staged to LDS
// (coalesced). V transposed via paired-key u32 writes (2-way = free).
// gate+mask read as ONE packed u32. No-max softmax (scores bounded).
__global__ __launch_bounds__(256) void flash_mfma(
    const short* __restrict__ qb, const short* __restrict__ kb,
    const short* __restrict__ vb, const uint32* __restrict__ gm,
    short* __restrict__ ctxb)
{
    __shared__ short Ks[64 * 72];   // [key][d]
    __shared__ short Vt[64 * 72];   // [d][key]
    __shared__ short Ps[4 * 16 * 72];
    const int q0 = blockIdx.x * 64;
    const int h = blockIdx.y, b = blockIdx.z;
    const int tid = threadIdx.x;
    const int w = tid >> 6, lane = tid & 63;
    const int quad = lane >> 4, lm = lane & 15;

    bf16x8 qf0, qf1;
    {
        const short* qrow = qb + ((size_t)(b * Ln + q0 + w * 16 + lm)) * Hn + h * DHn;
        qf0 = *(const bf16x8*)(qrow + quad * 8);
        qf1 = *(const bf16x8*)(qrow + 32 + quad * 8);
    }

    f32x4 o[4];
#pragma unroll
    for (int i = 0; i < 4; ++i) o[i] = (f32x4){0.f, 0.f, 0.f, 0.f};
    float lpart[4] = {0.f, 0.f, 0.f, 0.f};

    const uint32* gmb = gm + (size_t)b * Ln * Ln;
    const int qrow0 = q0 + w * 16 + quad * 4;
    const int kp = tid & 31;          // key-pair for V staging
    const int dg2 = tid >> 5;         // 0..7 d-group

    for (int k0 = 0; k0 < Ln; k0 += 64) {
        __syncthreads();   // prev iter's readers done with Ks/Vt
        // stage K [key][d]
        {
            int srow = tid >> 3, slot = tid & 7;
#pragma unroll
            for (int iss = 0; iss < 2; ++iss) {
                int r = srow + iss * 32;
                bf16x8 kv = *(const bf16x8*)(kb + ((size_t)(b * Ln + k0 + r)) * Hn + h * DHn + slot * 8);
                *(bf16x8*)(Ks + r * 72 + slot * 8) = kv;
            }
        }
        // stage V transposed via paired-key u32 writes: bank=(36d+kp)%32, 2-way free
        {
            const short* vbase = vb + ((size_t)(b * Ln + k0)) * Hn + h * DHn;
            const short* va_p = vbase + (size_t)(2 * kp) * Hn + dg2 * 8;
            const short* vc_p = vbase + (size_t)(2 * kp + 1) * Hn + dg2 * 8;
            bf16x8 va = *(const bf16x8*)va_p;
            bf16x8 vc = *(const bf16x8*)vc_p;
#pragma unroll
            for (int u = 0; u < 8; ++u) {
                uint32 pk2 = (uint32)(unsigned short)va[u] |
                             ((uint32)(unsigned short)vc[u] << 16);
                *(uint32*)&Vt[(dg2 * 8 + u) * 72 + 2 * kp] = pk2;
            }
        }
        __syncthreads();

        // S = Q K^T
        f32x4 s[4];
#pragma unroll
        for (int kt = 0; kt < 4; ++kt) {
            s[kt] = (f32x4){0.f, 0.f, 0.f, 0.f};
            bf16x8 b0 = *(const bf16x8*)(Ks + (kt * 16 + lm) * 72 + quad * 8);
            s[kt] = __builtin_amdgcn_mfma_f32_16x16x32_bf16(qf0, b0, s[kt], 0, 0, 0);
            bf16x8 b1 = *(const bf16x8*)(Ks + (kt * 16 + lm) * 72 + 32 + quad * 8);
            s[kt] = __builtin_amdgcn_mfma_f32_16x16x32_bf16(qf1, b1, s[kt], 0, 0, 0);
        }

        // p = exp(s*g + m) with packed gate/mask; accumulate l; write P
        short* pw = Ps + w * 16 * 72;
#pragma unroll
        for (int kt = 0; kt < 4; ++kt) {
            int col = k0 + kt * 16 + lm;
#pragma unroll
            for (int r = 0; r < 4; ++r) {
                uint32 pk2 = gmb[(size_t)(qrow0 + r) * Ln + col];
                float g = b2f((short)(pk2 & 0xFFFFu));
                float m = b2f((short)(pk2 >> 16));
                float pv = __expf(s[kt][r] * g + m);
                lpart[r] += pv;
                pw[(quad * 4 + r) * 72 + kt * 16 + lm] = f2b(pv);
            }
        }
        // PV
#pragma unroll
        for (int ks = 0; ks < 2; ++ks) {
            bf16x8 pa = *(const bf16x8*)(pw + lm * 72 + ks * 32 + quad * 8);
#pragma unroll
            for (int ot = 0; ot < 4; ++ot) {
                bf16x8 vv = *(const bf16x8*)(Vt + (ot * 16 + lm) * 72 + ks * 32 + quad * 8);
                o[ot] = __builtin_amdgcn_mfma_f32_16x16x32_bf16(pa, vv, o[ot], 0, 0, 0);
            }
        }
    }

    // final l reduction + normalize + store
#pragma unroll
    for (int r = 0; r < 4; ++r) {
        float lv = lpart[r];
#pragma unroll
        for (int off = 1; off < 16; off <<= 1) lv += __shfl_xor(lv, off, 64);
        float inv = 1.0f / lv;
        int row = b * Ln + qrow0 + r;
#pragma unroll
        for (int ot = 0; ot < 4; ++ot) {
            int d = h * DHn + ot * 16 + lm;
            ctxb[(size_t)row * Hn + d] = f2b(o[ot][r] * inv);
        }
    }
}

// ---------------- fused output projection + residual + LayerNorm ----------------
// block = 256 (4 waves); wave w owns rows [m0+w*16, +16) x ALL 256 cols.
// A/B frags straight from global (Wd is 128KB, L2-resident). No LDS, no barriers.
// LN reduce = 4 shuffles within the 16-lane column group.
__global__ __launch_bounds__(256) void outln_kernel(
    const short* __restrict__ ctxb, const short* __restrict__ wdb,
    const float* __restrict__ bd, const float* __restrict__ x,
    const float* __restrict__ lng, const float* __restrict__ lnb,
    float* __restrict__ out)
{
    const int m0 = blockIdx.x * 64;
    const int tid = threadIdx.x;
    const int w = tid >> 6, lane = tid & 63;
    const int quad = lane >> 4, lm = lane & 15;

    f32x4 acc[16];
#pragma unroll
    for (int i = 0; i < 16; ++i) acc[i] = (f32x4){0.f, 0.f, 0.f, 0.f};

    const short* arow = ctxb + (size_t)(m0 + w * 16 + lm) * Hn;
#pragma unroll
    for (int ks = 0; ks < 8; ++ks) {
        bf16x8 af = *(const bf16x8*)(arow + ks * 32 + quad * 8);
#pragma unroll
        for (int nt = 0; nt < 16; ++nt) {
            bf16x8 bf_ = *(const bf16x8*)(wdb + (size_t)(nt * 16 + lm) * Hn + ks * 32 + quad * 8);
            acc[nt] = __builtin_amdgcn_mfma_f32_16x16x32_bf16(af, bf_, acc[nt], 0, 0, 0);
        }
    }

    // bias + residual, accumulate LN sums
    float s1[4] = {0.f, 0.f, 0.f, 0.f}, s2[4] = {0.f, 0.f, 0.f, 0.f};
#pragma unroll
    for (int nt = 0; nt < 16; ++nt) {
        int col = nt * 16 + lm;
        float bv = bd[col];
#pragma unroll
        for (int r = 0; r < 4; ++r) {
            int row = m0 + w * 16 + quad * 4 + r;
            float v = acc[nt][r] + bv + x[(size_t)row * Hn + col];
            acc[nt][r] = v;
            s1[r] += v; s2[r] += v * v;
        }
    }
    float muv[4], rstd[4];
#pragma unroll
    for (int r = 0; r < 4; ++r) {
        float a = s1[r], b2 = s2[r];
#pragma unroll
        for (int off = 1; off < 16; off <<= 1) {
            a += __shfl_xor(a, off, 64);
            b2 += __shfl_xor(b2, off, 64);
        }
        float mu = a * (1.f / 256.f);
        float var = b2 * (1.f / 256.f) - mu * mu;
        muv[r] = mu;
        rstd[r] = rsqrtf(var + 1e-12f);
    }
#pragma unroll
    for (int nt = 0; nt < 16; ++nt) {
        int col = nt * 16 + lm;
        float gg = lng[col], bb = lnb[col];
#pragma unroll
        for (int r = 0; r < 4; ++r) {
            int row = m0 + w * 16 + quad * 4 + r;
            out[(size_t)row * Hn + col] = (acc[nt][r] - muv[r]) * rstd[r] * gg + bb;
        }
    }
}

// ---------------- prediction head ----------------
__global__ __launch_bounds__(256) void pred_kernel(const float* __restrict__ hs,
                                                   const int* __restrict__ lens,
                                                   const float* __restrict__ Wt,
                                                   const float* __restrict__ bt,
                                                   float* __restrict__ pred)
{
    const int b = blockIdx.x, t = threadIdx.x;
    int len = lens[b];
    float e1 = hs[((size_t)b * Ln + (len - 1)) * Hn + t];
    float e2 = hs[((size_t)b * Ln + (len - 2)) * Hn + t];
    float v = e1 * Wt[t] + e2 * Wt[Hn + t];
#pragma unroll
    for (int off = 32; off > 0; off >>= 1) v += __shfl_xor(v, off, 64);
    __shared__ float ps[4];
    if ((t & 63) == 0) ps[t >> 6] = v;
    __syncthreads();
    if (t == 0) pred[b] = ps[0] + ps[1] + ps[2] + ps[3] + bt[0];
}

extern "C" void kernel_launch(void* const* d_in, const int* in_sizes, int n_in,
                              void* d_out, int out_size, void* d_ws, size_t ws_size,
                              hipStream_t stream) {
    (void)in_sizes; (void)n_in; (void)out_size; (void)ws_size;
    const float* x    = (const float*)d_in[0];
    const float* tseq = (const float*)d_in[1];
    const float* mask = (const float*)d_in[2];
    const int*   lens = (const int*)d_in[3];
    const float* Wq = (const float*)d_in[4];  const float* bq = (const float*)d_in[5];
    const float* Wk = (const float*)d_in[6];  const float* bk = (const float*)d_in[7];
    const float* Wv = (const float*)d_in[8];  const float* bv = (const float*)d_in[9];
    const float* Wd = (const float*)d_in[10]; const float* bd = (const float*)d_in[11];
    const float* ln_g = (const float*)d_in[12]; const float* ln_b = (const float*)d_in[13];
    const float* Wtq = (const float*)d_in[14]; const float* btq = (const float*)d_in[15];
    const float* tw1 = (const float*)d_in[16]; const float* tb1 = (const float*)d_in[17];
    const float* tow1 = (const float*)d_in[18]; const float* tow2 = (const float*)d_in[19];
    const float* tob = (const float*)d_in[20];
    const float* Wt = (const float*)d_in[21]; const float* bt = (const float*)d_in[22];

    const size_t NLH = (size_t)Bn * Ln * Hn;   // 4194304
    const size_t NLL = (size_t)Bn * Ln * Ln;   // 8388608
    short* ws = (short*)d_ws;
    short* xb    = ws;
    short* wb    = xb + NLH;                   // 5*65536 shorts
    short* qb    = wb + 5 * 65536;
    short* kb    = qb + NLH;
    short* vb    = kb + NLH;
    short* tqb   = vb + NLH;
    uint32* gm   = (uint32*)(tqb + NLH);       // B*L*L u32 (even short offset -> 4B aligned)
    short* ctxb  = (short*)(gm + NLL);
    float* out   = (float*)d_out;

    dim3 blk(256);
    conv_kernel<<<dim3(4416), blk, 0, stream>>>(x, Wq, Wk, Wv, Wtq, Wd, xb, wb);
    proj_kernel<<<dim3(16, 256), blk, 0, stream>>>(xb, wb, bq, bk, bv, btq, qb, kb, vb, tqb);
    gate_kernel<<<dim3(8, 8, Bn), blk, 0, stream>>>(tqb, xb, tseq, mask, tw1, tb1, tow1, tow2, tob, gm);
    flash_mfma<<<dim3(8, NHn, Bn), blk, 0, stream>>>(qb, kb, vb, gm, ctxb);
    outln_kernel<<<dim3(256), blk, 0, stream>>>(ctxb, wb + 4 * 65536, bd, x, ln_g, ln_b, out);
    pred_kernel<<<dim3(Bn), blk, 0, stream>>>(out, lens, Wt, bt, out + NLH);
}